// Round 2
// baseline (833.315 us; speedup 1.0000x reference)
//
#include <hip/hip_runtime.h>
#include <hip/hip_bf16.h>
#include <math.h>

#define NB 32
#define NT 2048
#define NC 1024
#define NM 131072
#define TOPK 8
#define TCH 32              // t-chunks for mean
#define MBLK 256            // m rows per score block
#define SBLOCKS (NM / MBLK) // 512

// ws layout (float offsets)
#define OFF_PART 0
#define OFF_MEAN 1048576
#define OFF_Q    (OFF_MEAN + 32768)
#define OFF_CS   (OFF_Q + 32768)
#define OFF_CI   (OFF_CS + 131072)

__global__ __launch_bounds__(256) void mean_partial_k(const float* __restrict__ seg,
                                                      float* __restrict__ part) {
    int blk = blockIdx.x;            // 1024 = 32 b * 32 tc
    int b = blk >> 5, tc = blk & 31;
    int tid = threadIdx.x;
    const float4* src = (const float4*)(seg + ((size_t)b * NT + (size_t)tc * 64) * NC);
    float4 acc = make_float4(0.f, 0.f, 0.f, 0.f);
#pragma unroll 4
    for (int t = 0; t < 64; ++t) {
        float4 v = src[(size_t)t * 256 + tid];
        acc.x += v.x; acc.y += v.y; acc.z += v.z; acc.w += v.w;
    }
    ((float4*)(part + ((size_t)b * 32 + tc) * NC))[tid] = acc;
}

__global__ __launch_bounds__(256) void mean_finalize_k(const float* __restrict__ part,
                                                       float* __restrict__ mean) {
    int i = blockIdx.x * 256 + threadIdx.x;   // 32768
    int b = i >> 10, c = i & 1023;
    float s = 0.f;
#pragma unroll
    for (int tc = 0; tc < 32; ++tc) s += part[((size_t)b * 32 + tc) * NC + c];
    mean[i] = s * (1.0f / NT);
}

__global__ __launch_bounds__(256) void qproj_k(const float* __restrict__ mean,
                                               const float* __restrict__ Wq,
                                               const float* __restrict__ bq,
                                               float* __restrict__ q) {
    int wave = (blockIdx.x * 256 + threadIdx.x) >> 6;   // 2048 waves
    int lane = threadIdx.x & 63;
    int o0 = wave * 16;
    for (int j = 0; j < 16; ++j) {
        int o = o0 + j;                 // < 32768
        int b = o >> 10, i = o & 1023;
        const float4* wr = (const float4*)(Wq + (size_t)i * NC);
        const float4* mr = (const float4*)(mean + (size_t)b * NC);
        float acc = 0.f;
#pragma unroll
        for (int e = 0; e < 4; ++e) {
            float4 w4 = wr[lane * 4 + e];
            float4 m4 = mr[lane * 4 + e];
            acc += w4.x * m4.x + w4.y * m4.y + w4.z * m4.z + w4.w * m4.w;
        }
#pragma unroll
        for (int off = 32; off; off >>= 1) acc += __shfl_xor(acc, off);
        if (lane == 0) q[o] = acc + bq[i];
    }
}

// branchless top-8 insert, all-static indexing (keeps s/si in VGPRs)
#define BUBBLE8(v, vi, s, si)                                   \
    {                                                           \
        float _v = (v); int _vi = (vi);                         \
        _Pragma("unroll")                                       \
        for (int _u = 0; _u < 8; ++_u) {                        \
            bool _gt = _v > s[_u];                              \
            float _ts = _gt ? _v : s[_u];                       \
            int _ti = _gt ? _vi : si[_u];                       \
            _v = _gt ? s[_u] : _v;                              \
            _vi = _gt ? si[_u] : _vi;                           \
            s[_u] = _ts; si[_u] = _ti;                          \
        }                                                       \
    }

__global__ __launch_bounds__(256) void scores_topk_k(const float* __restrict__ memb,
                                                     const float* __restrict__ q,
                                                     float* __restrict__ candS,
                                                     int* __restrict__ candI) {
    // swizzled transposed tile: data (c4, m) stored at float4 index c4*MBLK + (m ^ c4)
    // write: 8-lane group has m fixed, c4=0..7 -> idx%8 = (m^c4)%8 distinct -> conflict-free
    // read:  c4 uniform, lanes tid -> (tid^c4) permutes within 8-groups -> conflict-free
    __shared__ float4 tile4[8 * MBLK];   // 32 KB
    int tid = threadIdx.x;
    int m0 = blockIdx.x * MBLK;
    float acc[NB];
#pragma unroll
    for (int b = 0; b < NB; ++b) acc[b] = 0.f;

    int c4w = tid & 7, rb = tid >> 3;
    for (int cc = 0; cc < NC / 32; ++cc) {
        int c0 = cc * 32;
        __syncthreads();   // protect previous tile reads
        {
            const float* gsrc = memb + (size_t)m0 * NC + c0 + c4w * 4;
#pragma unroll
            for (int it = 0; it < 8; ++it) {
                int m = rb + it * 32;
                float4 v = *(const float4*)(gsrc + (size_t)m * NC);
                tile4[c4w * MBLK + (m ^ c4w)] = v;
            }
        }
        __syncthreads();
#pragma unroll
        for (int c4 = 0; c4 < 8; ++c4) {
            float4 x = tile4[c4 * MBLK + (tid ^ c4)];
            const float* qc = q + c0 + c4 * 4;   // uniform -> s_load
#pragma unroll
            for (int b = 0; b < NB; ++b) {
                float4 qv = *(const float4*)(qc + (size_t)b * NC);  // uniform -> SGPR
                acc[b] = fmaf(x.x, qv.x, fmaf(x.y, qv.y, fmaf(x.z, qv.z, fmaf(x.w, qv.w, acc[b]))));
            }
        }
    }

    // scaled scores to LDS: [32 b][256 m]
    __syncthreads();
    float* fb = (float*)tile4;        // 8192 floats
#pragma unroll
    for (int b = 0; b < NB; ++b) fb[b * MBLK + tid] = acc[b] * 0.03125f;
    __syncthreads();

    // per-b top-8: 8 threads per b, each scans 32 scores (rotated by 4b -> 2-way max)
    {
        int b = tid >> 3, p = tid & 7;
        float s[8]; int si[8];
#pragma unroll
        for (int u = 0; u < 8; ++u) { s[u] = -INFINITY; si[u] = -1; }
        for (int j = 0; j < 32; ++j) {
            int ml = (p + j * 8 + b * 4) & 255;
            float v = fb[b * MBLK + ml];
            BUBBLE8(v, m0 + ml, s, si);
        }
        __syncthreads();   // all score reads done; reuse LDS for candidate lists
        float* cs = fb;                       // [256][8] floats at [0,2048)
        int* ci = (int*)(fb + 2048);          // [256][8] ints  at [2048,4096)
#pragma unroll
        for (int u = 0; u < 8; ++u) { cs[tid * 8 + u] = s[u]; ci[tid * 8 + u] = si[u]; }
        __syncthreads();
        float* csA = fb + 4096;               // [64][8]
        int* ciA = (int*)(fb + 4608);
        if (tid < 64) {
            int b2 = tid >> 1, half = tid & 1;
            float s2[8]; int si2[8];
#pragma unroll
            for (int u = 0; u < 8; ++u) { s2[u] = -INFINITY; si2[u] = -1; }
            int t0 = b2 * 8 + half * 4;
            for (int tt = 0; tt < 4; ++tt)
#pragma unroll
                for (int u = 0; u < 8; ++u)
                    BUBBLE8(cs[(t0 + tt) * 8 + u], ci[(t0 + tt) * 8 + u], s2, si2);
#pragma unroll
            for (int u = 0; u < 8; ++u) { csA[tid * 8 + u] = s2[u]; ciA[tid * 8 + u] = si2[u]; }
        }
        __syncthreads();
        if (tid < 32) {
            int b3 = tid;
            float s3[8]; int si3[8];
#pragma unroll
            for (int u = 0; u < 8; ++u) { s3[u] = -INFINITY; si3[u] = -1; }
            for (int j = 0; j < 16; ++j)
                BUBBLE8(csA[b3 * 16 + j], ciA[b3 * 16 + j], s3, si3);
#pragma unroll
            for (int u = 0; u < 8; ++u) {
                candS[((size_t)b3 * SBLOCKS + blockIdx.x) * 8 + u] = s3[u];
                candI[((size_t)b3 * SBLOCKS + blockIdx.x) * 8 + u] = si3[u];
            }
        }
    }
}

__global__ __launch_bounds__(256) void finalize_k(const float* __restrict__ candS,
                                                  const int* __restrict__ candI,
                                                  const float* __restrict__ memb,
                                                  float* __restrict__ out) {
    __shared__ float cs[2048 + 256 + 32 + 8];
    __shared__ int ci[2048 + 256 + 32 + 8];
    int b = blockIdx.x, tid = threadIdx.x;
    const float* S = candS + (size_t)b * (SBLOCKS * 8);
    const int* I = candI + (size_t)b * (SBLOCKS * 8);
    float s[8]; int si[8];
#pragma unroll
    for (int u = 0; u < 8; ++u) { s[u] = -INFINITY; si[u] = -1; }
    for (int j = 0; j < 16; ++j)
        BUBBLE8(S[tid * 16 + j], I[tid * 16 + j], s, si);
#pragma unroll
    for (int u = 0; u < 8; ++u) { cs[tid * 8 + u] = s[u]; ci[tid * 8 + u] = si[u]; }
    __syncthreads();
    if (tid < 32) {
        float s2[8]; int si2[8];
#pragma unroll
        for (int u = 0; u < 8; ++u) { s2[u] = -INFINITY; si2[u] = -1; }
        for (int j = 0; j < 64; ++j)
            BUBBLE8(cs[tid * 64 + j], ci[tid * 64 + j], s2, si2);
#pragma unroll
        for (int u = 0; u < 8; ++u) { cs[2048 + tid * 8 + u] = s2[u]; ci[2048 + tid * 8 + u] = si2[u]; }
    }
    __syncthreads();
    if (tid < 4) {
        float s3[8]; int si3[8];
#pragma unroll
        for (int u = 0; u < 8; ++u) { s3[u] = -INFINITY; si3[u] = -1; }
        for (int j = 0; j < 64; ++j)
            BUBBLE8(cs[2048 + tid * 64 + j], ci[2048 + tid * 64 + j], s3, si3);
#pragma unroll
        for (int u = 0; u < 8; ++u) { cs[2304 + tid * 8 + u] = s3[u]; ci[2304 + tid * 8 + u] = si3[u]; }
    }
    __syncthreads();
    if (tid == 0) {
        float s4[8]; int si4[8];
#pragma unroll
        for (int u = 0; u < 8; ++u) { s4[u] = -INFINITY; si4[u] = -1; }
        for (int j = 0; j < 32; ++j)
            BUBBLE8(cs[2304 + j], ci[2304 + j], s4, si4);
        // softmax over sorted-desc top-8 (s4[0] is max)
        float m = s4[0], sum = 0.f;
        float w[8];
#pragma unroll
        for (int u = 0; u < 8; ++u) { w[u] = __expf(s4[u] - m); sum += w[u]; }
        float inv = 1.0f / sum;
#pragma unroll
        for (int u = 0; u < 8; ++u) { cs[2336 + u] = w[u] * inv; ci[2336 + u] = si4[u]; }
    }
    __syncthreads();
    float wv[8]; int ix[8];
#pragma unroll
    for (int u = 0; u < 8; ++u) { wv[u] = cs[2336 + u]; ix[u] = ci[2336 + u]; }
    float4 o = make_float4(0.f, 0.f, 0.f, 0.f);
#pragma unroll
    for (int u = 0; u < 8; ++u) {
        float4 r = ((const float4*)(memb + (size_t)ix[u] * NC))[tid];
        o.x = fmaf(wv[u], r.x, o.x);
        o.y = fmaf(wv[u], r.y, o.y);
        o.z = fmaf(wv[u], r.z, o.z);
        o.w = fmaf(wv[u], r.w, o.w);
    }
    ((float4*)(out + (size_t)b * NC))[tid] = o;
}

extern "C" void kernel_launch(void* const* d_in, const int* in_sizes, int n_in,
                              void* d_out, int out_size, void* d_ws, size_t ws_size,
                              hipStream_t stream) {
    const float* seg  = (const float*)d_in[0];
    const float* Wq   = (const float*)d_in[1];
    const float* bq   = (const float*)d_in[2];
    const float* memb = (const float*)d_in[3];
    float* ws = (float*)d_ws;
    float* part  = ws + OFF_PART;
    float* mean  = ws + OFF_MEAN;
    float* q     = ws + OFF_Q;
    float* candS = ws + OFF_CS;
    int*   candI = (int*)(ws + OFF_CI);
    float* out = (float*)d_out;

    mean_partial_k<<<NB * TCH, 256, 0, stream>>>(seg, part);
    mean_finalize_k<<<(NB * NC) / 256, 256, 0, stream>>>(part, mean);
    qproj_k<<<512, 256, 0, stream>>>(mean, Wq, bq, q);
    scores_topk_k<<<SBLOCKS, 256, 0, stream>>>(memb, q, candS, candI);
    finalize_k<<<NB, 256, 0, stream>>>(candS, candI, memb, out);
}

// Round 3
// 417.898 us; speedup vs baseline: 1.9941x; 1.9941x over previous
//
#include <hip/hip_runtime.h>
#include <hip/hip_bf16.h>
#include <math.h>

#define NB 32
#define NT 2048
#define NC 1024
#define NM 131072
#define TOPK 8
#define TCH 32              // t-chunks for mean
#define MBLK 256            // m rows per score block
#define SBLOCKS (NM / MBLK) // 512
#define TROW 257            // padded tile row (float4 units)

// ws layout (float offsets)
#define OFF_PART 0
#define OFF_MEAN 1048576
#define OFF_Q    (OFF_MEAN + 32768)
#define OFF_CS   (OFF_Q + 32768)
#define OFF_CI   (OFF_CS + 131072)

__global__ __launch_bounds__(256) void mean_partial_k(const float* __restrict__ seg,
                                                      float* __restrict__ part) {
    int blk = blockIdx.x;            // 1024 = 32 b * 32 tc
    int b = blk >> 5, tc = blk & 31;
    int tid = threadIdx.x;
    const float4* src = (const float4*)(seg + ((size_t)b * NT + (size_t)tc * 64) * NC);
    float4 acc = make_float4(0.f, 0.f, 0.f, 0.f);
#pragma unroll 4
    for (int t = 0; t < 64; ++t) {
        float4 v = src[(size_t)t * 256 + tid];
        acc.x += v.x; acc.y += v.y; acc.z += v.z; acc.w += v.w;
    }
    ((float4*)(part + ((size_t)b * 32 + tc) * NC))[tid] = acc;
}

__global__ __launch_bounds__(256) void mean_finalize_k(const float* __restrict__ part,
                                                       float* __restrict__ mean) {
    int i = blockIdx.x * 256 + threadIdx.x;   // 32768
    int b = i >> 10, c = i & 1023;
    float s = 0.f;
#pragma unroll
    for (int tc = 0; tc < 32; ++tc) s += part[((size_t)b * 32 + tc) * NC + c];
    mean[i] = s * (1.0f / NT);
}

__global__ __launch_bounds__(256) void qproj_k(const float* __restrict__ mean,
                                               const float* __restrict__ Wq,
                                               const float* __restrict__ bq,
                                               float* __restrict__ q) {
    int wave = (blockIdx.x * 256 + threadIdx.x) >> 6;   // 2048 waves
    int lane = threadIdx.x & 63;
    int o0 = wave * 16;
    for (int j = 0; j < 16; ++j) {
        int o = o0 + j;                 // < 32768
        int b = o >> 10, i = o & 1023;
        const float4* wr = (const float4*)(Wq + (size_t)i * NC);
        const float4* mr = (const float4*)(mean + (size_t)b * NC);
        float acc = 0.f;
#pragma unroll
        for (int e = 0; e < 4; ++e) {
            float4 w4 = wr[lane * 4 + e];
            float4 m4 = mr[lane * 4 + e];
            acc += w4.x * m4.x + w4.y * m4.y + w4.z * m4.z + w4.w * m4.w;
        }
#pragma unroll
        for (int off = 32; off; off >>= 1) acc += __shfl_xor(acc, off);
        if (lane == 0) q[o] = acc + bq[i];
    }
}

// branchless top-8 insert, all-static indexing (keeps s/si in VGPRs)
#define BUBBLE8(v, vi, s, si)                                   \
    {                                                           \
        float _v = (v); int _vi = (vi);                         \
        _Pragma("unroll")                                       \
        for (int _u = 0; _u < 8; ++_u) {                        \
            bool _gt = _v > s[_u];                              \
            float _ts = _gt ? _v : s[_u];                       \
            int _ti = _gt ? _vi : si[_u];                       \
            _v = _gt ? s[_u] : _v;                              \
            _vi = _gt ? si[_u] : _vi;                           \
            s[_u] = _ts; si[_u] = _ti;                          \
        }                                                       \
    }

// GEMM-style scores: block = 256 m-rows x 32 b, K=1024 in 64 chunks of 16 c.
// Wave w owns batch octet b0=8w; thread owns 4 m-rows (mr*64+lane).
// Per c4-step: 4 tile ds_read_b128 + 8 q broadcast reads per 128 FMAs -> VALU-bound.
// Reg-staged double-buffer: issue next-chunk global loads BEFORE compute (T14).
__global__ __launch_bounds__(256) void scores_topk_k(const float* __restrict__ memb,
                                                     const float* __restrict__ q,
                                                     float* __restrict__ candS,
                                                     int* __restrict__ candI) {
    __shared__ float4 smem[2 * 4 * TROW + 2 * 128];   // 36,992 B
    int tid = threadIdx.x;
    int lane = tid & 63;
    int b0 = (tid >> 6) * 8;
    int m0 = blockIdx.x * MBLK;
    int c4s = tid & 3, ms = tid >> 2;   // staging coords: c-quad, row-ish

    float acc[8][4];
#pragma unroll
    for (int bb = 0; bb < 8; ++bb)
#pragma unroll
        for (int mr = 0; mr < 4; ++mr) acc[bb][mr] = 0.f;

    const float* mbase = memb + (size_t)m0 * NC + c4s * 4;
    const float* qbase = q + (size_t)ms * NC + c4s * 4;   // deref only when tid<128

    float4 rt[4]; float4 rq;
    // prologue: stage chunk 0
#pragma unroll
    for (int it = 0; it < 4; ++it)
        rt[it] = *(const float4*)(mbase + (size_t)(it * 64 + ms) * NC);
    if (tid < 128) rq = *(const float4*)qbase;
    {
        float4* tbn = smem;
        float4* qbn = smem + 8 * TROW;
#pragma unroll
        for (int it = 0; it < 4; ++it) tbn[c4s * TROW + it * 64 + ms] = rt[it];
        if (tid < 128) qbn[tid] = rq;
    }
    __syncthreads();

    for (int cc = 0; cc < 64; ++cc) {
        float4* tbp = smem + (cc & 1) * (4 * TROW);
        float4* qbp = smem + 8 * TROW + (cc & 1) * 128;
        if (cc < 63) {   // issue next-chunk loads early; consumed after compute
            int c0 = (cc + 1) * 16;
#pragma unroll
            for (int it = 0; it < 4; ++it)
                rt[it] = *(const float4*)(mbase + (size_t)(it * 64 + ms) * NC + c0);
            if (tid < 128) rq = *(const float4*)(qbase + c0);
        }
#pragma unroll
        for (int c4 = 0; c4 < 4; ++c4) {
            float4 x[4];
#pragma unroll
            for (int mr = 0; mr < 4; ++mr) x[mr] = tbp[c4 * TROW + mr * 64 + lane];
#pragma unroll
            for (int bb = 0; bb < 8; ++bb) {
                float4 qv = qbp[(b0 + bb) * 4 + c4];   // same-addr broadcast
#pragma unroll
                for (int mr = 0; mr < 4; ++mr)
                    acc[bb][mr] = fmaf(x[mr].x, qv.x, fmaf(x[mr].y, qv.y,
                                  fmaf(x[mr].z, qv.z, fmaf(x[mr].w, qv.w, acc[bb][mr]))));
            }
        }
        if (cc < 63) {
            float4* tbn = smem + ((cc + 1) & 1) * (4 * TROW);
            float4* qbn = smem + 8 * TROW + ((cc + 1) & 1) * 128;
#pragma unroll
            for (int it = 0; it < 4; ++it) tbn[c4s * TROW + it * 64 + ms] = rt[it];
            if (tid < 128) qbn[tid] = rq;
        }
        __syncthreads();
    }

    // scaled scores to LDS: [32 b][256 m]
    float* fb = (float*)smem;        // 8192 floats = 32 KB, fits in 36.9 KB
#pragma unroll
    for (int bb = 0; bb < 8; ++bb)
#pragma unroll
        for (int mr = 0; mr < 4; ++mr)
            fb[(b0 + bb) * MBLK + mr * 64 + lane] = acc[bb][mr] * 0.03125f;
    __syncthreads();

    // per-b top-8: 8 threads per b, each scans 32 scores (rotated by 4b -> <=2-way)
    {
        int b = tid >> 3, p = tid & 7;
        float s[8]; int si[8];
#pragma unroll
        for (int u = 0; u < 8; ++u) { s[u] = -INFINITY; si[u] = -1; }
        for (int j = 0; j < 32; ++j) {
            int ml = (p + j * 8 + b * 4) & 255;
            float v = fb[b * MBLK + ml];
            BUBBLE8(v, m0 + ml, s, si);
        }
        __syncthreads();   // all score reads done; reuse LDS for candidate lists
        float* cs = fb;                       // [256][8] floats at [0,2048)
        int* ci = (int*)(fb + 2048);          // [256][8] ints  at [2048,4096)
#pragma unroll
        for (int u = 0; u < 8; ++u) { cs[tid * 8 + u] = s[u]; ci[tid * 8 + u] = si[u]; }
        __syncthreads();
        float* csA = fb + 4096;               // [64][8]
        int* ciA = (int*)(fb + 4608);
        if (tid < 64) {
            int b2 = tid >> 1, half = tid & 1;
            float s2[8]; int si2[8];
#pragma unroll
            for (int u = 0; u < 8; ++u) { s2[u] = -INFINITY; si2[u] = -1; }
            int t0 = b2 * 8 + half * 4;
            for (int tt = 0; tt < 4; ++tt)
#pragma unroll
                for (int u = 0; u < 8; ++u)
                    BUBBLE8(cs[(t0 + tt) * 8 + u], ci[(t0 + tt) * 8 + u], s2, si2);
#pragma unroll
            for (int u = 0; u < 8; ++u) { csA[tid * 8 + u] = s2[u]; ciA[tid * 8 + u] = si2[u]; }
        }
        __syncthreads();
        if (tid < 32) {
            int b3 = tid;
            float s3[8]; int si3[8];
#pragma unroll
            for (int u = 0; u < 8; ++u) { s3[u] = -INFINITY; si3[u] = -1; }
            for (int j = 0; j < 16; ++j)
                BUBBLE8(csA[b3 * 16 + j], ciA[b3 * 16 + j], s3, si3);
#pragma unroll
            for (int u = 0; u < 8; ++u) {
                candS[((size_t)b3 * SBLOCKS + blockIdx.x) * 8 + u] = s3[u];
                candI[((size_t)b3 * SBLOCKS + blockIdx.x) * 8 + u] = si3[u];
            }
        }
    }
}

__global__ __launch_bounds__(256) void finalize_k(const float* __restrict__ candS,
                                                  const int* __restrict__ candI,
                                                  const float* __restrict__ memb,
                                                  float* __restrict__ out) {
    __shared__ float cs[2048 + 256 + 32 + 8];
    __shared__ int ci[2048 + 256 + 32 + 8];
    int b = blockIdx.x, tid = threadIdx.x;
    const float* S = candS + (size_t)b * (SBLOCKS * 8);
    const int* I = candI + (size_t)b * (SBLOCKS * 8);
    float s[8]; int si[8];
#pragma unroll
    for (int u = 0; u < 8; ++u) { s[u] = -INFINITY; si[u] = -1; }
    for (int j = 0; j < 16; ++j)
        BUBBLE8(S[tid * 16 + j], I[tid * 16 + j], s, si);
#pragma unroll
    for (int u = 0; u < 8; ++u) { cs[tid * 8 + u] = s[u]; ci[tid * 8 + u] = si[u]; }
    __syncthreads();
    if (tid < 32) {
        float s2[8]; int si2[8];
#pragma unroll
        for (int u = 0; u < 8; ++u) { s2[u] = -INFINITY; si2[u] = -1; }
        for (int j = 0; j < 64; ++j)
            BUBBLE8(cs[tid * 64 + j], ci[tid * 64 + j], s2, si2);
#pragma unroll
        for (int u = 0; u < 8; ++u) { cs[2048 + tid * 8 + u] = s2[u]; ci[2048 + tid * 8 + u] = si2[u]; }
    }
    __syncthreads();
    if (tid < 4) {
        float s3[8]; int si3[8];
#pragma unroll
        for (int u = 0; u < 8; ++u) { s3[u] = -INFINITY; si3[u] = -1; }
        for (int j = 0; j < 64; ++j)
            BUBBLE8(cs[2048 + tid * 64 + j], ci[2048 + tid * 64 + j], s3, si3);
#pragma unroll
        for (int u = 0; u < 8; ++u) { cs[2304 + tid * 8 + u] = s3[u]; ci[2304 + tid * 8 + u] = si3[u]; }
    }
    __syncthreads();
    if (tid == 0) {
        float s4[8]; int si4[8];
#pragma unroll
        for (int u = 0; u < 8; ++u) { s4[u] = -INFINITY; si4[u] = -1; }
        for (int j = 0; j < 32; ++j)
            BUBBLE8(cs[2304 + j], ci[2304 + j], s4, si4);
        // softmax over sorted-desc top-8 (s4[0] is max)
        float m = s4[0], sum = 0.f;
        float w[8];
#pragma unroll
        for (int u = 0; u < 8; ++u) { w[u] = __expf(s4[u] - m); sum += w[u]; }
        float inv = 1.0f / sum;
#pragma unroll
        for (int u = 0; u < 8; ++u) { cs[2336 + u] = w[u] * inv; ci[2336 + u] = si4[u]; }
    }
    __syncthreads();
    float wv[8]; int ix[8];
#pragma unroll
    for (int u = 0; u < 8; ++u) { wv[u] = cs[2336 + u]; ix[u] = ci[2336 + u]; }
    float4 o = make_float4(0.f, 0.f, 0.f, 0.f);
#pragma unroll
    for (int u = 0; u < 8; ++u) {
        float4 r = ((const float4*)(memb + (size_t)ix[u] * NC))[tid];
        o.x = fmaf(wv[u], r.x, o.x);
        o.y = fmaf(wv[u], r.y, o.y);
        o.z = fmaf(wv[u], r.z, o.z);
        o.w = fmaf(wv[u], r.w, o.w);
    }
    ((float4*)(out + (size_t)b * NC))[tid] = o;
}

extern "C" void kernel_launch(void* const* d_in, const int* in_sizes, int n_in,
                              void* d_out, int out_size, void* d_ws, size_t ws_size,
                              hipStream_t stream) {
    const float* seg  = (const float*)d_in[0];
    const float* Wq   = (const float*)d_in[1];
    const float* bq   = (const float*)d_in[2];
    const float* memb = (const float*)d_in[3];
    float* ws = (float*)d_ws;
    float* part  = ws + OFF_PART;
    float* mean  = ws + OFF_MEAN;
    float* q     = ws + OFF_Q;
    float* candS = ws + OFF_CS;
    int*   candI = (int*)(ws + OFF_CI);
    float* out = (float*)d_out;

    mean_partial_k<<<NB * TCH, 256, 0, stream>>>(seg, part);
    mean_finalize_k<<<(NB * NC) / 256, 256, 0, stream>>>(part, mean);
    qproj_k<<<512, 256, 0, stream>>>(mean, Wq, bq, q);
    scores_topk_k<<<SBLOCKS, 256, 0, stream>>>(memb, q, candS, candI);
    finalize_k<<<NB, 256, 0, stream>>>(candS, candI, memb, out);
}

// Round 4
// 412.264 us; speedup vs baseline: 2.0213x; 1.0137x over previous
//
#include <hip/hip_runtime.h>
#include <hip/hip_bf16.h>
#include <math.h>

#define NB 32
#define NT 2048
#define NC 1024
#define NM 131072
#define TOPK 8
#define TCH 32              // t-chunks for mean
#define MBLK 256            // m rows per score block
#define SBLOCKS (NM / MBLK) // 512
#define TROW 257            // padded tile row (float4 units)

// ws layout (float offsets)
#define OFF_PART 0
#define OFF_MEAN 1048576
#define OFF_Q    (OFF_MEAN + 32768)
#define OFF_CS   (OFF_Q + 32768)
#define OFF_CI   (OFF_CS + 131072)

__global__ __launch_bounds__(256) void mean_partial_k(const float* __restrict__ seg,
                                                      float* __restrict__ part) {
    int blk = blockIdx.x;            // 1024 = 32 b * 32 tc
    int b = blk >> 5, tc = blk & 31;
    int tid = threadIdx.x;
    const float4* src = (const float4*)(seg + ((size_t)b * NT + (size_t)tc * 64) * NC);
    float4 acc = make_float4(0.f, 0.f, 0.f, 0.f);
#pragma unroll 4
    for (int t = 0; t < 64; ++t) {
        float4 v = src[(size_t)t * 256 + tid];
        acc.x += v.x; acc.y += v.y; acc.z += v.z; acc.w += v.w;
    }
    ((float4*)(part + ((size_t)b * 32 + tc) * NC))[tid] = acc;
}

__global__ __launch_bounds__(256) void mean_finalize_k(const float* __restrict__ part,
                                                       float* __restrict__ mean) {
    int i = blockIdx.x * 256 + threadIdx.x;   // 32768
    int b = i >> 10, c = i & 1023;
    float s = 0.f;
#pragma unroll
    for (int tc = 0; tc < 32; ++tc) s += part[((size_t)b * 32 + tc) * NC + c];
    mean[i] = s * (1.0f / NT);
}

__global__ __launch_bounds__(256) void qproj_k(const float* __restrict__ mean,
                                               const float* __restrict__ Wq,
                                               const float* __restrict__ bq,
                                               float* __restrict__ q) {
    int wave = (blockIdx.x * 256 + threadIdx.x) >> 6;   // 2048 waves
    int lane = threadIdx.x & 63;
    int o0 = wave * 16;
    for (int j = 0; j < 16; ++j) {
        int o = o0 + j;                 // < 32768
        int b = o >> 10, i = o & 1023;
        const float4* wr = (const float4*)(Wq + (size_t)i * NC);
        const float4* mr = (const float4*)(mean + (size_t)b * NC);
        float acc = 0.f;
#pragma unroll
        for (int e = 0; e < 4; ++e) {
            float4 w4 = wr[lane * 4 + e];
            float4 m4 = mr[lane * 4 + e];
            acc += w4.x * m4.x + w4.y * m4.y + w4.z * m4.z + w4.w * m4.w;
        }
#pragma unroll
        for (int off = 32; off; off >>= 1) acc += __shfl_xor(acc, off);
        if (lane == 0) q[o] = acc + bq[i];
    }
}

// branchless top-8 insert, all-static indexing (keeps s/si in VGPRs)
#define BUBBLE8(v, vi, s, si)                                   \
    {                                                           \
        float _v = (v); int _vi = (vi);                         \
        _Pragma("unroll")                                       \
        for (int _u = 0; _u < 8; ++_u) {                        \
            bool _gt = _v > s[_u];                              \
            float _ts = _gt ? _v : s[_u];                       \
            int _ti = _gt ? _vi : si[_u];                       \
            _v = _gt ? s[_u] : _v;                              \
            _vi = _gt ? si[_u] : _vi;                           \
            s[_u] = _ts; si[_u] = _ti;                          \
        }                                                       \
    }

// Scores: block = 256 m x 32 b. Wave w owns b-octet b0=8w.
// Lane split: mgrp=lane&15 (m-rows mgrp+16*mr), cgrp=lane>>4 (c-quad within chunk16).
// q is LANE-PRIVATE in registers (loaded from global, L2-hot) -> zero LDS q traffic.
// x-tile LDS-staged double-buffered: 1 ds_read_b128 per 32 FMAs.
// End: 2x shfl_xor partial-sum reduce over the 4 cgrp lanes.
__global__ __launch_bounds__(256, 2) void scores_topk_k(const float* __restrict__ memb,
                                                        const float* __restrict__ q,
                                                        float* __restrict__ candS,
                                                        int* __restrict__ candI) {
    __shared__ float4 smem[2 * 4 * TROW];   // 32,896 B (two 4xTROW tile buffers)
    int tid = threadIdx.x;
    int lane = tid & 63;
    int b0 = (tid >> 6) * 8;
    int mgrp = lane & 15, cgrp = lane >> 4;
    int m0 = blockIdx.x * MBLK;
    int c4s = tid & 3, ms = tid >> 2;   // staging coords

    float acc[16][8];
#pragma unroll
    for (int mr = 0; mr < 16; ++mr)
#pragma unroll
        for (int bb = 0; bb < 8; ++bb) acc[mr][bb] = 0.f;

    const float* mbase = memb + (size_t)m0 * NC + c4s * 4;
    const float* qbase = q + (size_t)b0 * NC + cgrp * 4;

    float4 rt[4];
    // prologue: stage chunk 0
#pragma unroll
    for (int it = 0; it < 4; ++it)
        rt[it] = *(const float4*)(mbase + (size_t)(it * 64 + ms) * NC);
#pragma unroll
    for (int it = 0; it < 4; ++it) smem[c4s * TROW + it * 64 + ms] = rt[it];
    __syncthreads();

    for (int cc = 0; cc < 64; ++cc) {
        const float4* tbp = smem + (cc & 1) * (4 * TROW);
        // q for THIS chunk: lane-private, L2-hot, one cache line per instr
        float4 qc[8];
#pragma unroll
        for (int bb = 0; bb < 8; ++bb)
            qc[bb] = *(const float4*)(qbase + (size_t)bb * NC + cc * 16);
        // tile stage loads for next chunk (HBM), consumed after compute
        if (cc < 63) {
            int c0 = (cc + 1) * 16;
#pragma unroll
            for (int it = 0; it < 4; ++it)
                rt[it] = *(const float4*)(mbase + (size_t)(it * 64 + ms) * NC + c0);
        }
#pragma unroll
        for (int mr = 0; mr < 16; ++mr) {
            float4 x = tbp[cgrp * TROW + mgrp + 16 * mr];
#pragma unroll
            for (int bb = 0; bb < 8; ++bb)
                acc[mr][bb] = fmaf(x.x, qc[bb].x, fmaf(x.y, qc[bb].y,
                              fmaf(x.z, qc[bb].z, fmaf(x.w, qc[bb].w, acc[mr][bb]))));
        }
        if (cc < 63) {
            float4* tbn = smem + ((cc + 1) & 1) * (4 * TROW);
#pragma unroll
            for (int it = 0; it < 4; ++it) tbn[c4s * TROW + it * 64 + ms] = rt[it];
        }
        __syncthreads();
    }

    // cross-lane reduce over the 4 cgrp partials; write scores [32 b][256 m]
    float* fb = (float*)smem;        // 8192 floats = 32 KB
#pragma unroll
    for (int mr = 0; mr < 16; ++mr)
#pragma unroll
        for (int bb = 0; bb < 8; ++bb) {
            float v = acc[mr][bb];
            v += __shfl_xor(v, 16);
            v += __shfl_xor(v, 32);
            if ((mr & 3) == cgrp)
                fb[(b0 + bb) * MBLK + mgrp + 16 * mr] = v * 0.03125f;
        }
    __syncthreads();

    // per-b top-8: 8 threads per b, each scans 32 scores (rotated by 4b -> <=2-way)
    {
        int b = tid >> 3, p = tid & 7;
        float s[8]; int si[8];
#pragma unroll
        for (int u = 0; u < 8; ++u) { s[u] = -INFINITY; si[u] = -1; }
        for (int j = 0; j < 32; ++j) {
            int ml = (p + j * 8 + b * 4) & 255;
            float v = fb[b * MBLK + ml];
            BUBBLE8(v, m0 + ml, s, si);
        }
        __syncthreads();   // all score reads done; reuse LDS for candidate lists
        float* cs = fb;                       // [256][8] floats at [0,2048)
        int* ci = (int*)(fb + 2048);          // [256][8] ints  at [2048,4096)
#pragma unroll
        for (int u = 0; u < 8; ++u) { cs[tid * 8 + u] = s[u]; ci[tid * 8 + u] = si[u]; }
        __syncthreads();
        float* csA = fb + 4096;               // [64][8]
        int* ciA = (int*)(fb + 4608);
        if (tid < 64) {
            int b2 = tid >> 1, half = tid & 1;
            float s2[8]; int si2[8];
#pragma unroll
            for (int u = 0; u < 8; ++u) { s2[u] = -INFINITY; si2[u] = -1; }
            int t0 = b2 * 8 + half * 4;
            for (int tt = 0; tt < 4; ++tt)
#pragma unroll
                for (int u = 0; u < 8; ++u)
                    BUBBLE8(cs[(t0 + tt) * 8 + u], ci[(t0 + tt) * 8 + u], s2, si2);
#pragma unroll
            for (int u = 0; u < 8; ++u) { csA[tid * 8 + u] = s2[u]; ciA[tid * 8 + u] = si2[u]; }
        }
        __syncthreads();
        if (tid < 32) {
            int b3 = tid;
            float s3[8]; int si3[8];
#pragma unroll
            for (int u = 0; u < 8; ++u) { s3[u] = -INFINITY; si3[u] = -1; }
            for (int j = 0; j < 16; ++j)
                BUBBLE8(csA[b3 * 16 + j], ciA[b3 * 16 + j], s3, si3);
#pragma unroll
            for (int u = 0; u < 8; ++u) {
                candS[((size_t)b3 * SBLOCKS + blockIdx.x) * 8 + u] = s3[u];
                candI[((size_t)b3 * SBLOCKS + blockIdx.x) * 8 + u] = si3[u];
            }
        }
    }
}

__global__ __launch_bounds__(256) void finalize_k(const float* __restrict__ candS,
                                                  const int* __restrict__ candI,
                                                  const float* __restrict__ memb,
                                                  float* __restrict__ out) {
    __shared__ float cs[2048 + 256 + 32 + 8];
    __shared__ int ci[2048 + 256 + 32 + 8];
    int b = blockIdx.x, tid = threadIdx.x;
    const float* S = candS + (size_t)b * (SBLOCKS * 8);
    const int* I = candI + (size_t)b * (SBLOCKS * 8);
    float s[8]; int si[8];
#pragma unroll
    for (int u = 0; u < 8; ++u) { s[u] = -INFINITY; si[u] = -1; }
    for (int j = 0; j < 16; ++j)
        BUBBLE8(S[tid * 16 + j], I[tid * 16 + j], s, si);
#pragma unroll
    for (int u = 0; u < 8; ++u) { cs[tid * 8 + u] = s[u]; ci[tid * 8 + u] = si[u]; }
    __syncthreads();
    if (tid < 32) {
        float s2[8]; int si2[8];
#pragma unroll
        for (int u = 0; u < 8; ++u) { s2[u] = -INFINITY; si2[u] = -1; }
        for (int j = 0; j < 64; ++j)
            BUBBLE8(cs[tid * 64 + j], ci[tid * 64 + j], s2, si2);
#pragma unroll
        for (int u = 0; u < 8; ++u) { cs[2048 + tid * 8 + u] = s2[u]; ci[2048 + tid * 8 + u] = si2[u]; }
    }
    __syncthreads();
    if (tid < 4) {
        float s3[8]; int si3[8];
#pragma unroll
        for (int u = 0; u < 8; ++u) { s3[u] = -INFINITY; si3[u] = -1; }
        for (int j = 0; j < 64; ++j)
            BUBBLE8(cs[2048 + tid * 64 + j], ci[2048 + tid * 64 + j], s3, si3);
#pragma unroll
        for (int u = 0; u < 8; ++u) { cs[2304 + tid * 8 + u] = s3[u]; ci[2304 + tid * 8 + u] = si3[u]; }
    }
    __syncthreads();
    if (tid == 0) {
        float s4[8]; int si4[8];
#pragma unroll
        for (int u = 0; u < 8; ++u) { s4[u] = -INFINITY; si4[u] = -1; }
        for (int j = 0; j < 32; ++j)
            BUBBLE8(cs[2304 + j], ci[2304 + j], s4, si4);
        // softmax over sorted-desc top-8 (s4[0] is max)
        float m = s4[0], sum = 0.f;
        float w[8];
#pragma unroll
        for (int u = 0; u < 8; ++u) { w[u] = __expf(s4[u] - m); sum += w[u]; }
        float inv = 1.0f / sum;
#pragma unroll
        for (int u = 0; u < 8; ++u) { cs[2336 + u] = w[u] * inv; ci[2336 + u] = si4[u]; }
    }
    __syncthreads();
    float wv[8]; int ix[8];
#pragma unroll
    for (int u = 0; u < 8; ++u) { wv[u] = cs[2336 + u]; ix[u] = ci[2336 + u]; }
    float4 o = make_float4(0.f, 0.f, 0.f, 0.f);
#pragma unroll
    for (int u = 0; u < 8; ++u) {
        float4 r = ((const float4*)(memb + (size_t)ix[u] * NC))[tid];
        o.x = fmaf(wv[u], r.x, o.x);
        o.y = fmaf(wv[u], r.y, o.y);
        o.z = fmaf(wv[u], r.z, o.z);
        o.w = fmaf(wv[u], r.w, o.w);
    }
    ((float4*)(out + (size_t)b * NC))[tid] = o;
}

extern "C" void kernel_launch(void* const* d_in, const int* in_sizes, int n_in,
                              void* d_out, int out_size, void* d_ws, size_t ws_size,
                              hipStream_t stream) {
    const float* seg  = (const float*)d_in[0];
    const float* Wq   = (const float*)d_in[1];
    const float* bq   = (const float*)d_in[2];
    const float* memb = (const float*)d_in[3];
    float* ws = (float*)d_ws;
    float* part  = ws + OFF_PART;
    float* mean  = ws + OFF_MEAN;
    float* q     = ws + OFF_Q;
    float* candS = ws + OFF_CS;
    int*   candI = (int*)(ws + OFF_CI);
    float* out = (float*)d_out;

    mean_partial_k<<<NB * TCH, 256, 0, stream>>>(seg, part);
    mean_finalize_k<<<(NB * NC) / 256, 256, 0, stream>>>(part, mean);
    qproj_k<<<512, 256, 0, stream>>>(mean, Wq, bq, q);
    scores_topk_k<<<SBLOCKS, 256, 0, stream>>>(memb, q, candS, candI);
    finalize_k<<<NB, 256, 0, stream>>>(candS, candI, memb, out);
}

// Round 5
// 353.115 us; speedup vs baseline: 2.3599x; 1.1675x over previous
//
#include <hip/hip_runtime.h>
#include <hip/hip_bf16.h>
#include <math.h>

#define NB 32
#define NT 2048
#define NC 1024
#define NM 131072
#define TOPK 8
#define TCH 32              // t-chunks for mean
#define MBLK 128            // m rows per score block
#define SBLOCKS (NM / MBLK) // 1024
#define TROW 129            // padded tile row (float4 units)

// ws layout (float offsets). candS/candI OVERLAY part (part is dead after
// mean_finalize_k; scores_topk_k runs after qproj_k on the same stream).
#define OFF_PART 0
#define OFF_CS   0
#define OFF_CI   262144
#define OFF_MEAN 1048576
#define OFF_Q    (OFF_MEAN + 32768)

__global__ __launch_bounds__(256) void mean_partial_k(const float* __restrict__ seg,
                                                      float* __restrict__ part) {
    int blk = blockIdx.x;            // 1024 = 32 b * 32 tc
    int b = blk >> 5, tc = blk & 31;
    int tid = threadIdx.x;
    const float4* src = (const float4*)(seg + ((size_t)b * NT + (size_t)tc * 64) * NC);
    float4 acc = make_float4(0.f, 0.f, 0.f, 0.f);
#pragma unroll 4
    for (int t = 0; t < 64; ++t) {
        float4 v = src[(size_t)t * 256 + tid];
        acc.x += v.x; acc.y += v.y; acc.z += v.z; acc.w += v.w;
    }
    ((float4*)(part + ((size_t)b * 32 + tc) * NC))[tid] = acc;
}

__global__ __launch_bounds__(256) void mean_finalize_k(const float* __restrict__ part,
                                                       float* __restrict__ mean) {
    int i = blockIdx.x * 256 + threadIdx.x;   // 32768
    int b = i >> 10, c = i & 1023;
    float s = 0.f;
#pragma unroll
    for (int tc = 0; tc < 32; ++tc) s += part[((size_t)b * 32 + tc) * NC + c];
    mean[i] = s * (1.0f / NT);
}

__global__ __launch_bounds__(256) void qproj_k(const float* __restrict__ mean,
                                               const float* __restrict__ Wq,
                                               const float* __restrict__ bq,
                                               float* __restrict__ q) {
    int wave = (blockIdx.x * 256 + threadIdx.x) >> 6;   // 2048 waves
    int lane = threadIdx.x & 63;
    int o0 = wave * 16;
    for (int j = 0; j < 16; ++j) {
        int o = o0 + j;                 // < 32768
        int b = o >> 10, i = o & 1023;
        const float4* wr = (const float4*)(Wq + (size_t)i * NC);
        const float4* mr = (const float4*)(mean + (size_t)b * NC);
        float acc = 0.f;
#pragma unroll
        for (int e = 0; e < 4; ++e) {
            float4 w4 = wr[lane * 4 + e];
            float4 m4 = mr[lane * 4 + e];
            acc += w4.x * m4.x + w4.y * m4.y + w4.z * m4.z + w4.w * m4.w;
        }
#pragma unroll
        for (int off = 32; off; off >>= 1) acc += __shfl_xor(acc, off);
        if (lane == 0) q[o] = acc + bq[i];
    }
}

// branchless top-8 insert, all-static indexing (keeps s/si in VGPRs)
#define BUBBLE8(v, vi, s, si)                                   \
    {                                                           \
        float _v = (v); int _vi = (vi);                         \
        _Pragma("unroll")                                       \
        for (int _u = 0; _u < 8; ++_u) {                        \
            bool _gt = _v > s[_u];                              \
            float _ts = _gt ? _v : s[_u];                       \
            int _ti = _gt ? _vi : si[_u];                       \
            _v = _gt ? s[_u] : _v;                              \
            _vi = _gt ? si[_u] : _vi;                           \
            s[_u] = _ts; si[_u] = _ti;                          \
        }                                                       \
    }

// Scores: block = 128 m x 32 b. 4 waves = (mhalf, bhalf); lanes mgrp16 x cgrp4.
// Thread: acc[4 m][16 b] over its c-quad slice. q lane-private from global (L1/L2-hot),
// loaded in two bb-halves of 8 to cap live registers. x-tile LDS double-buffered:
// 4 ds_read_b128 + 2 ds_write per 256 v_fma -> LDS pipe ~0.6 of VALU.
// Staging: wave w writes c4-quad w, 64 consecutive float4s -> conflict-free.
__global__ __launch_bounds__(256, 2) void scores_topk_k(const float* __restrict__ memb,
                                                        const float* __restrict__ q,
                                                        float* __restrict__ candS,
                                                        int* __restrict__ candI) {
    __shared__ __align__(16) float smemf[5760];   // 23 KB: tiles(4128f) | scores(4096f) | tree(5760f)
    float4* smem = (float4*)smemf;
    int tid = threadIdx.x, lane = tid & 63, wid = tid >> 6;
    int mhalf = wid & 1, bhalf = wid >> 1;
    int mgrp = lane & 15, cgrp = lane >> 4;
    int m0 = blockIdx.x * MBLK;

    float acc[4][16];
#pragma unroll
    for (int mr = 0; mr < 4; ++mr)
#pragma unroll
        for (int bb = 0; bb < 16; ++bb) acc[mr][bb] = 0.f;

    // staging: this wave loads rows (lane, lane+64) at c-quad wid
    const float* sbase = memb + (size_t)(m0 + lane) * NC + wid * 4;
    const float* qbase = q + (size_t)(bhalf * 16) * NC + cgrp * 4;

    float4 rt0, rt1;
    rt0 = *(const float4*)(sbase);
    rt1 = *(const float4*)(sbase + 64 * NC);
    smem[wid * TROW + lane] = rt0;
    smem[wid * TROW + 64 + lane] = rt1;
    __syncthreads();

    for (int cc = 0; cc < 64; ++cc) {
        const float4* tbp = smem + (cc & 1) * (4 * TROW);
        if (cc < 63) {   // prefetch next chunk into regs; LDS-write after compute
            const float* s2 = sbase + (cc + 1) * 16;
            rt0 = *(const float4*)(s2);
            rt1 = *(const float4*)(s2 + 64 * NC);
        }
        float4 x[4];
#pragma unroll
        for (int mr = 0; mr < 4; ++mr)
            x[mr] = tbp[cgrp * TROW + mhalf * 64 + mgrp + 16 * mr];
#pragma unroll
        for (int h = 0; h < 2; ++h) {
            float4 qc[8];
#pragma unroll
            for (int bb = 0; bb < 8; ++bb)
                qc[bb] = *(const float4*)(qbase + (size_t)(h * 8 + bb) * NC + cc * 16);
#pragma unroll
            for (int mr = 0; mr < 4; ++mr)
#pragma unroll
                for (int bb = 0; bb < 8; ++bb)
                    acc[mr][h * 8 + bb] = fmaf(x[mr].x, qc[bb].x, fmaf(x[mr].y, qc[bb].y,
                                          fmaf(x[mr].z, qc[bb].z, fmaf(x[mr].w, qc[bb].w,
                                          acc[mr][h * 8 + bb]))));
        }
        if (cc < 63) {
            float4* tbn = smem + ((cc + 1) & 1) * (4 * TROW);
            tbn[wid * TROW + lane] = rt0;
            tbn[wid * TROW + 64 + lane] = rt1;
        }
        __syncthreads();
    }

    // reduce over 4 cgrp lanes; write scores [32 b][128 m]
    float* fb = smemf;   // 4096 floats
#pragma unroll
    for (int mr = 0; mr < 4; ++mr)
#pragma unroll
        for (int bb = 0; bb < 16; ++bb) {
            float v = acc[mr][bb];
            v += __shfl_xor(v, 16);
            v += __shfl_xor(v, 32);
            if (cgrp == (bb & 3))
                fb[(bhalf * 16 + bb) * MBLK + mhalf * 64 + mgrp + 16 * mr] = v * 0.03125f;
        }
    __syncthreads();

    // per-b top-8: 8 threads per b, each scans 16 scores (rotated -> <=2-way banks)
    {
        int b = tid >> 3, p = tid & 7;
        float s[8]; int si[8];
#pragma unroll
        for (int u = 0; u < 8; ++u) { s[u] = -INFINITY; si[u] = -1; }
#pragma unroll
        for (int j = 0; j < 16; ++j) {
            int ml = (p + j * 8 + b * 4) & 127;
            float v = fb[b * MBLK + ml];
            BUBBLE8(v, m0 + ml, s, si);
        }
        __syncthreads();   // scores consumed; reuse LDS for candidate tree (stride 9)
        float* cs = smemf;                    // [256][9] floats at [0,2304)
        int* ci = (int*)(smemf + 2304);       // [256][9] ints  at [2304,4608)
#pragma unroll
        for (int u = 0; u < 8; ++u) { cs[tid * 9 + u] = s[u]; ci[tid * 9 + u] = si[u]; }
        __syncthreads();
        float* csA = smemf + 4608;            // [64][9]
        int* ciA = (int*)(smemf + 5184);      // [64][9] -> ends 5760
        if (tid < 64) {
            float s2[8]; int si2[8];
#pragma unroll
            for (int u = 0; u < 8; ++u) { s2[u] = -INFINITY; si2[u] = -1; }
            int t0 = (tid >> 1) * 8 + (tid & 1) * 4;
            for (int tt = 0; tt < 4; ++tt)
#pragma unroll
                for (int u = 0; u < 8; ++u)
                    BUBBLE8(cs[(t0 + tt) * 9 + u], ci[(t0 + tt) * 9 + u], s2, si2);
#pragma unroll
            for (int u = 0; u < 8; ++u) { csA[tid * 9 + u] = s2[u]; ciA[tid * 9 + u] = si2[u]; }
        }
        __syncthreads();
        if (tid < 32) {
            float s3[8]; int si3[8];
#pragma unroll
            for (int u = 0; u < 8; ++u) { s3[u] = -INFINITY; si3[u] = -1; }
            for (int j = 0; j < 16; ++j)
                BUBBLE8(csA[(tid * 2 + (j >> 3)) * 9 + (j & 7)],
                        ciA[(tid * 2 + (j >> 3)) * 9 + (j & 7)], s3, si3);
#pragma unroll
            for (int u = 0; u < 8; ++u) {
                candS[((size_t)tid * SBLOCKS + blockIdx.x) * 8 + u] = s3[u];
                candI[((size_t)tid * SBLOCKS + blockIdx.x) * 8 + u] = si3[u];
            }
        }
    }
}

__global__ __launch_bounds__(256) void finalize_k(const float* __restrict__ candS,
                                                  const int* __restrict__ candI,
                                                  const float* __restrict__ memb,
                                                  float* __restrict__ out) {
    __shared__ float cs[2048 + 256 + 32 + 8];
    __shared__ int ci[2048 + 256 + 32 + 8];
    int b = blockIdx.x, tid = threadIdx.x;
    const float* S = candS + (size_t)b * (SBLOCKS * 8);
    const int* I = candI + (size_t)b * (SBLOCKS * 8);
    float s[8]; int si[8];
#pragma unroll
    for (int u = 0; u < 8; ++u) { s[u] = -INFINITY; si[u] = -1; }
    for (int j = 0; j < 32; ++j)
        BUBBLE8(S[tid * 32 + j], I[tid * 32 + j], s, si);
#pragma unroll
    for (int u = 0; u < 8; ++u) { cs[tid * 8 + u] = s[u]; ci[tid * 8 + u] = si[u]; }
    __syncthreads();
    if (tid < 32) {
        float s2[8]; int si2[8];
#pragma unroll
        for (int u = 0; u < 8; ++u) { s2[u] = -INFINITY; si2[u] = -1; }
        for (int j = 0; j < 64; ++j)
            BUBBLE8(cs[tid * 64 + j], ci[tid * 64 + j], s2, si2);
#pragma unroll
        for (int u = 0; u < 8; ++u) { cs[2048 + tid * 8 + u] = s2[u]; ci[2048 + tid * 8 + u] = si2[u]; }
    }
    __syncthreads();
    if (tid < 4) {
        float s3[8]; int si3[8];
#pragma unroll
        for (int u = 0; u < 8; ++u) { s3[u] = -INFINITY; si3[u] = -1; }
        for (int j = 0; j < 64; ++j)
            BUBBLE8(cs[2048 + tid * 64 + j], ci[2048 + tid * 64 + j], s3, si3);
#pragma unroll
        for (int u = 0; u < 8; ++u) { cs[2304 + tid * 8 + u] = s3[u]; ci[2304 + tid * 8 + u] = si3[u]; }
    }
    __syncthreads();
    if (tid == 0) {
        float s4[8]; int si4[8];
#pragma unroll
        for (int u = 0; u < 8; ++u) { s4[u] = -INFINITY; si4[u] = -1; }
        for (int j = 0; j < 32; ++j)
            BUBBLE8(cs[2304 + j], ci[2304 + j], s4, si4);
        // softmax over sorted-desc top-8 (s4[0] is max)
        float m = s4[0], sum = 0.f;
        float w[8];
#pragma unroll
        for (int u = 0; u < 8; ++u) { w[u] = __expf(s4[u] - m); sum += w[u]; }
        float inv = 1.0f / sum;
#pragma unroll
        for (int u = 0; u < 8; ++u) { cs[2336 + u] = w[u] * inv; ci[2336 + u] = si4[u]; }
    }
    __syncthreads();
    float wv[8]; int ix[8];
#pragma unroll
    for (int u = 0; u < 8; ++u) { wv[u] = cs[2336 + u]; ix[u] = ci[2336 + u]; }
    float4 o = make_float4(0.f, 0.f, 0.f, 0.f);
#pragma unroll
    for (int u = 0; u < 8; ++u) {
        float4 r = ((const float4*)(memb + (size_t)ix[u] * NC))[tid];
        o.x = fmaf(wv[u], r.x, o.x);
        o.y = fmaf(wv[u], r.y, o.y);
        o.z = fmaf(wv[u], r.z, o.z);
        o.w = fmaf(wv[u], r.w, o.w);
    }
    ((float4*)(out + (size_t)b * NC))[tid] = o;
}

extern "C" void kernel_launch(void* const* d_in, const int* in_sizes, int n_in,
                              void* d_out, int out_size, void* d_ws, size_t ws_size,
                              hipStream_t stream) {
    const float* seg  = (const float*)d_in[0];
    const float* Wq   = (const float*)d_in[1];
    const float* bq   = (const float*)d_in[2];
    const float* memb = (const float*)d_in[3];
    float* ws = (float*)d_ws;
    float* part  = ws + OFF_PART;
    float* mean  = ws + OFF_MEAN;
    float* q     = ws + OFF_Q;
    float* candS = ws + OFF_CS;           // overlays part (safe: part dead by then)
    int*   candI = (int*)(ws + OFF_CI);
    float* out = (float*)d_out;

    mean_partial_k<<<NB * TCH, 256, 0, stream>>>(seg, part);
    mean_finalize_k<<<(NB * NC) / 256, 256, 0, stream>>>(part, mean);
    qproj_k<<<512, 256, 0, stream>>>(mean, Wq, bq, q);
    scores_topk_k<<<SBLOCKS, 256, 0, stream>>>(memb, q, candS, candI);
    finalize_k<<<NB, 256, 0, stream>>>(candS, candI, memb, out);
}